// Round 14
// baseline (85.479 us; speedup 1.0000x reference)
//
#include <hip/hip_runtime.h>
#include <math.h>

typedef unsigned short u16;
typedef unsigned int   u32;

using bf16x8 = __attribute__((ext_vector_type(8))) short;
using f32x4  = __attribute__((ext_vector_type(4))) float;

#define NB   64
#define NE   8
#define DIN  320
#define NP   196
#define CK   768
#define CN   768
#define NKT  24      // K-chunks of 32

#define GATE_BLOCKS  8
#define WPACK_BLOCKS 2304   // 8*48*24 chunks * 64 lanes / 256
#define APACK_BLOCKS 1024   // 64 images x 16 frag-rows

__device__ __forceinline__ u16 f2bf(float f) {
    u32 u = __builtin_bit_cast(u32, f);
    u += 0x7fffu + ((u >> 16) & 1u);
    return (u16)(u >> 16);
}

__device__ __forceinline__ void gload16(const void* g, void* l) {
    __builtin_amdgcn_global_load_lds(
        (const __attribute__((address_space(1))) void*)g,
        (__attribute__((address_space(3))) void*)l, 16, 0, 0);
}

// ---------------- prep1: gate1 + B-pack + A-pack patchify (R11/R12-verified) ----------------
// packed chunk = 1KB: lane l holds 16B = 8 bf16 along k;
//   A chunk(b, fr, kb) at ((b*16+fr)*24+kb)*1024:  row = fr*16+(l&15), k = kb*32+(l>>4)*8
//   B chunk(e, fnG, kb) at ((e*48+fnG)*24+kb)*1024: col = fnG*16+(l&15), k same
__global__ __launch_bounds__(256) void prep1_kernel(
    const float* __restrict__ x,
    const float* __restrict__ g,
    const float* __restrict__ noise,
    const float* __restrict__ w_gate,
    const float* __restrict__ w_noise,
    const float* __restrict__ w_exp,
    float* __restrict__ gCl, float* __restrict__ gSd, float* __restrict__ gNy,
    u16* __restrict__ apk,
    u16* __restrict__ wpk)
{
    __shared__ char smem[24704];    // union: gate 23KB | apack 24KB
    const int t = threadIdx.x;
    int bid = blockIdx.x;

    if (bid < GATE_BLOCKS) {
        float (*sW)[NE + 1]  = (float (*)[NE + 1])smem;
        float (*sWn)[NE + 1] = sW + DIN;
        for (int i = t; i < DIN * NE; i += 256) {
            sW[i >> 3][i & 7]  = w_gate[i];
            sWn[i >> 3][i & 7] = w_noise[i];
        }
        __syncthreads();
        const int pair = t >> 2, q = t & 3;
        const int bl = pair >> 3, e = pair & 7;
        const int b = bid * 8 + bl;
        float cl = 0.f, nz = 0.f;
        const float* gr = g + b * DIN + q * 80;
        #pragma unroll 4
        for (int j = 0; j < 80; ++j) {
            float gv = gr[j];
            cl = fmaf(gv, sW[q * 80 + j][e], cl);
            nz = fmaf(gv, sWn[q * 80 + j][e], nz);
        }
        cl += __shfl_xor(cl, 1); cl += __shfl_xor(cl, 2);
        nz += __shfl_xor(nz, 1); nz += __shfl_xor(nz, 2);
        if (q == 0) {
            int p = b * NE + e;
            // jax.nn.softplus == max(x,0)+log1p(exp(-|x|))
            float sd = fmaxf(nz, 0.f) + log1pf(expf(-fabsf(nz))) + 0.01f;
            gCl[p] = cl; gSd[p] = sd;
            gNy[p] = fmaf(noise[p], sd, cl);
        }
        return;
    }
    bid -= GATE_BLOCKS;

    if (bid < WPACK_BLOCKS) {
        int idx = bid * 256 + t;
        int chunk = idx >> 6, l = idx & 63;
        int e   = chunk / 1152;
        int rem = chunk % 1152;
        int fnG = rem / 24;
        int kb  = rem % 24;
        const float* src = w_exp + ((size_t)(e * CN + fnG * 16 + (l & 15))) * CK
                         + kb * 32 + (l >> 4) * 8;
        float4 f0 = *reinterpret_cast<const float4*>(src);
        float4 f1 = *reinterpret_cast<const float4*>(src + 4);
        uint4 o;
        o.x = (u32)f2bf(f0.x) | ((u32)f2bf(f0.y) << 16);
        o.y = (u32)f2bf(f0.z) | ((u32)f2bf(f0.w) << 16);
        o.z = (u32)f2bf(f1.x) | ((u32)f2bf(f1.y) << 16);
        o.w = (u32)f2bf(f1.z) | ((u32)f2bf(f1.w) << 16);
        *reinterpret_cast<uint4*>(wpk + (size_t)chunk * 512 + l * 8) = o;
        return;
    }
    bid -= WPACK_BLOCKS;

    // ---- A-pack patchify: block = (image b, frag-row fr) ----
    {
        char* pk = smem;   // 24KB staging
        const int b  = bid >> 4;
        const int fr = bid & 15;
        #pragma unroll
        for (int s = 0; s < 3; ++s) {
            int u  = t + s * 256;            // u = (lr*3 + c)*16 + ph
            int lr = u / 48;
            int c  = (u >> 4) % 3;
            int ph = u & 15;
            int p  = fr * 16 + lr; if (p > NP - 1) p = NP - 1;  // pad rows: dup of 195
            const float* src = x + ((size_t)(b * 3 + c) * 224 + (p / 14) * 16 + ph) * 224
                                 + (p % 14) * 16;
            float4 f0 = *reinterpret_cast<const float4*>(src);
            float4 f1 = *reinterpret_cast<const float4*>(src + 4);
            float4 f2 = *reinterpret_cast<const float4*>(src + 8);
            float4 f3 = *reinterpret_cast<const float4*>(src + 12);
            uint4 o0, o1;
            o0.x = (u32)f2bf(f0.x) | ((u32)f2bf(f0.y) << 16);
            o0.y = (u32)f2bf(f0.z) | ((u32)f2bf(f0.w) << 16);
            o0.z = (u32)f2bf(f1.x) | ((u32)f2bf(f1.y) << 16);
            o0.w = (u32)f2bf(f1.z) | ((u32)f2bf(f1.w) << 16);
            o1.x = (u32)f2bf(f2.x) | ((u32)f2bf(f2.y) << 16);
            o1.y = (u32)f2bf(f2.z) | ((u32)f2bf(f2.w) << 16);
            o1.z = (u32)f2bf(f3.x) | ((u32)f2bf(f3.y) << 16);
            o1.w = (u32)f2bf(f3.z) | ((u32)f2bf(f3.w) << 16);
            // k = c*256 + ph*16 + pw -> kb = c*8 + (ph>>1), lk0 = (ph&1)*2
            u32 base = (u32)((c * 8 + (ph >> 1)) * 1024 + ((ph & 1) * 2) * 256 + lr * 16);
            *reinterpret_cast<uint4*>(pk + base)       = o0;
            *reinterpret_cast<uint4*>(pk + base + 256) = o1;
        }
        __syncthreads();
        char* dst = (char*)apk + ((size_t)(b * 16 + fr) * 24) * 1024;
        #pragma unroll
        for (int s = 0; s < 6; ++s)
            *reinterpret_cast<uint4*>(dst + t * 16 + s * 4096) =
                *reinterpret_cast<const uint4*>(pk + t * 16 + s * 4096);
    }
}

// ---------------- gate2: top-2, probs, loss, perm + per-expert offsets ----------------
__global__ __launch_bounds__(512) void gate2_kernel(
    const float* __restrict__ gCl,
    const float* __restrict__ gSd,
    const float* __restrict__ gNy,
    int* __restrict__ perm,
    int* __restrict__ offs,
    float* __restrict__ loss_out)
{
    __shared__ float sNy[NB][NE];
    __shared__ float sProb[NB][NE];
    __shared__ int   sTop[NB];
    __shared__ float sImp[NE], sLoad[NE];
    const int t = threadIdx.x;            // 512 = one (b,e) pair each
    const int b = t >> 3, e = t & 7;
    float cl = gCl[t], sd = gSd[t], ny = gNy[t];
    sNy[b][e] = ny;
    __syncthreads();
    float v1 = -1e30f, v2 = -1e30f; int i1 = 0;
    #pragma unroll
    for (int k2 = 0; k2 < NE; ++k2) {
        float v = sNy[b][k2];
        if (v > v1) { v2 = v1; v1 = v; i1 = k2; }
        else if (v > v2) { v2 = v; }
    }
    if (e == 0) sTop[b] = i1;
    // is_in: noisy > 2nd-largest (thr_in=v2); else threshold = largest (v1)
    float thr = (ny > v2) ? v2 : v1;
    float z = (cl - thr) / sd;
    sProb[b][e] = 0.5f * (1.0f + erff(z * 0.7071067811865476f));
    __syncthreads();
    if (t < NE) {
        float imp = 0.f, ld = 0.f;
        for (int i = 0; i < NB; ++i) {
            imp += (sTop[i] == t) ? 1.0f : 0.0f;
            ld  += sProb[i][t];
        }
        sImp[t] = imp; sLoad[t] = ld;
    }
    __syncthreads();
    if (t == 0) {
        float mi = 0.f, ml = 0.f;
        for (int k2 = 0; k2 < NE; ++k2) { mi += sImp[k2]; ml += sLoad[k2]; }
        mi *= (1.0f / NE); ml *= (1.0f / NE);
        float vi = 0.f, vl = 0.f;
        for (int k2 = 0; k2 < NE; ++k2) {
            float d1 = sImp[k2] - mi;  vi += d1 * d1;
            float d2 = sLoad[k2] - ml; vl += d2 * d2;
        }
        vi *= (1.0f / (NE - 1)); vl *= (1.0f / (NE - 1));  // ddof=1
        loss_out[0] = (vi / (mi * mi + 1e-10f) + vl / (ml * ml + 1e-10f)) * 0.01f;
        // expert-sorted stable permutation + offsets (counting sort)
        int off[NE + 1]; off[0] = 0;
        #pragma unroll
        for (int k2 = 0; k2 < NE; ++k2) off[k2 + 1] = off[k2] + (int)sImp[k2];
        #pragma unroll
        for (int k2 = 0; k2 <= NE; ++k2) offs[k2] = off[k2];
        int cur[NE];
        #pragma unroll
        for (int k2 = 0; k2 < NE; ++k2) cur[k2] = off[k2];
        for (int i = 0; i < NB; ++i) perm[cur[sTop[i]]++] = i;
    }
}

// ---------------- persistent-B grouped expert GEMM ----------------
// 192 blocks: e = id&7 (-> XCD co-location), nt = (id>>3)&7 (96-col slab),
// grp = id>>6 (0..2, round-robin over the expert's images). 512 thr = 8 waves:
// hw = w>>2 picks image slot {0,1} of a pair, wq = w&3 picks 64-row quarter.
// B panel (96 x 768) staged ONCE into LDS as 144 packed 1KB chunks (conflict-
// free lane-linear reads); then per image-pair a barrier-free K-loop:
// A-frags = coalesced 1KB chunk loads from apk (L2-resident per XCD),
// B-frags = ds_read, 24 MFMA per step, reg double-buffered.
__global__ void __launch_bounds__(512, 2) gemm_kernel(
    const u16* __restrict__ apk,
    const u16* __restrict__ wpk,
    const float* __restrict__ b_exp,
    const int* __restrict__ perm,
    const int* __restrict__ offs,
    float* __restrict__ out)
{
    extern __shared__ char sB[];   // 147456 B = 6 fn x 24 kb x 1KB

    const int id  = blockIdx.x;
    const int e   = id & 7;
    const int nt  = (id >> 3) & 7;
    const int grp = id >> 6;

    const int beg = offs[e] + grp;
    const int end = offs[e + 1];
    if (beg >= end) return;          // uniform: whole block exits

    const int t  = threadIdx.x;
    const int l  = t & 63;
    const int w  = t >> 6;
    const int hw = w >> 2;           // image slot within pair
    const int wq = w & 3;            // 64-row quarter

    // ---- stage B panel: 144KB contiguous from wpk (linear, lane*16) ----
    {
        const char* src = (const char*)wpk + ((size_t)(e * 48 + nt * 6) * 24) * 1024;
        #pragma unroll
        for (int s = 0; s < 18; ++s)
            gload16(src + s * 8192 + t * 16, sB + s * 8192 + (w * 1024 + l * 16));
    }
    asm volatile("s_waitcnt vmcnt(0)" ::: "memory");
    __syncthreads();

    const u32 bl16 = (u32)(l * 16);
    const int r4 = (l >> 4) * 4;

    // ---- image-pair loop (no barriers inside) ----
    for (int i = beg; i < end; i += 6) {
        const int  bA  = perm[i];
        const bool has2 = (i + 3 < end);
        const int  bI  = hw ? (has2 ? perm[i + 3] : bA) : bA;
        const bool doSt = hw ? has2 : true;

        const char* aBase = (const char*)apk
                          + ((size_t)((bI * 16 + wq * 4) * 24)) * 1024 + l * 16;

        f32x4 acc[4][6];
        #pragma unroll
        for (int fm = 0; fm < 4; ++fm)
            #pragma unroll
            for (int j = 0; j < 6; ++j)
                acc[fm][j] = (f32x4){0.f, 0.f, 0.f, 0.f};

        bf16x8 aC[4], bC[6], aN[4], bN[6];

        auto LDA = [&](bf16x8 (&ra)[4], bf16x8 (&rb)[6], int kb) {
            if (kb > NKT - 1) kb = NKT - 1;    // tail clamp: redundant, harmless
            #pragma unroll
            for (int fm = 0; fm < 4; ++fm)
                ra[fm] = *reinterpret_cast<const bf16x8*>(aBase + (fm * 24 + kb) * 1024);
            #pragma unroll
            for (int j = 0; j < 6; ++j)
                rb[j] = *reinterpret_cast<const bf16x8*>(sB + (u32)((j * 24 + kb) * 1024) + bl16);
        };
        auto MM = [&](bf16x8 (&ra)[4], bf16x8 (&rb)[6]) {
            __builtin_amdgcn_s_setprio(1);
            #pragma unroll
            for (int fm = 0; fm < 4; ++fm)
                #pragma unroll
                for (int j = 0; j < 6; ++j)
                    acc[fm][j] = __builtin_amdgcn_mfma_f32_16x16x32_bf16(
                        ra[fm], rb[j], acc[fm][j], 0, 0, 0);
            __builtin_amdgcn_s_setprio(0);
        };

        LDA(aC, bC, 0);
        #pragma unroll 1
        for (int kb = 0; kb < NKT; kb += 2) {
            LDA(aN, bN, kb + 1);
            MM(aC, bC);
            LDA(aC, bC, kb + 2);
            MM(aN, bN);
        }

        if (doSt) {
            #pragma unroll
            for (int fm = 0; fm < 4; ++fm) {
                const int mb = wq * 64 + fm * 16 + r4;
                #pragma unroll
                for (int j = 0; j < 6; ++j) {
                    const int col = nt * 96 + j * 16 + (l & 15);
                    const float bias = b_exp[e * CN + col];
                    #pragma unroll
                    for (int q = 0; q < 4; ++q) {
                        const int mrow = mb + q;
                        if (mrow < NP) {
                            float vv = acc[fm][j][q] + bias;
                            if (vv == 0.0f) vv = 2.220446049250313e-16f;
                            out[((size_t)bI * NP + mrow) * CN + col] = vv;
                        }
                    }
                }
            }
        }
    }
}

extern "C" void kernel_launch(void* const* d_in, const int* in_sizes, int n_in,
                              void* d_out, int out_size, void* d_ws, size_t ws_size,
                              hipStream_t stream) {
    const float* x       = (const float*)d_in[0];
    const float* g       = (const float*)d_in[1];
    const float* noise   = (const float*)d_in[2];
    const float* w_gate  = (const float*)d_in[3];
    const float* w_noise = (const float*)d_in[4];
    const float* w_exp   = (const float*)d_in[5];
    const float* b_exp   = (const float*)d_in[6];
    float* out = (float*)d_out;

    char* ws = (char*)d_ws;
    int*   perm = (int*)ws;                     // 256 B
    int*   offs = (int*)(ws + 256);             // 64 B
    float* gCl  = (float*)(ws + 512);
    float* gSd  = (float*)(ws + 2560);
    float* gNy  = (float*)(ws + 4608);
    u16*   apk  = (u16*)(ws + 8192);                                // 25.2 MB
    u16*   wpk  = (u16*)(ws + 8192 + (size_t)64 * 16 * 24 * 1024);  // 9.4 MB

    hipFuncSetAttribute((const void*)gemm_kernel,
                        hipFuncAttributeMaxDynamicSharedMemorySize, 147456);

    hipLaunchKernelGGL(prep1_kernel,
                       dim3(GATE_BLOCKS + WPACK_BLOCKS + APACK_BLOCKS), dim3(256), 0, stream,
                       x, g, noise, w_gate, w_noise, w_exp, gCl, gSd, gNy, apk, wpk);
    hipLaunchKernelGGL(gate2_kernel, dim3(1), dim3(512), 0, stream,
                       gCl, gSd, gNy, perm, offs, out + (size_t)NB * NP * CN);
    hipLaunchKernelGGL(gemm_kernel, dim3(192), dim3(512), 147456, stream,
                       apk, wpk, b_exp, perm, offs, out);
}

// Round 15
// 64.048 us; speedup vs baseline: 1.3346x; 1.3346x over previous
//
#include <hip/hip_runtime.h>
#include <math.h>

typedef unsigned short u16;
typedef unsigned int   u32;

using bf16x8 = __attribute__((ext_vector_type(8))) short;
using f32x4  = __attribute__((ext_vector_type(4))) float;

#define NB   64
#define NE   8
#define DIN  320
#define NP   196
#define CK   768
#define CN   768
#define ESTR (768 * 768)
#define NKT2 12       // K-tiles of 64

#define GATE_BLOCKS  8
#define WCONV_BLOCKS 1152   // 8*768*768 / (16*256)
#define PATCH_BLOCKS 2352   // 64*196*48 / 256

__device__ __forceinline__ u16 f2bf(float f) {
    u32 u = __builtin_bit_cast(u32, f);
    u += 0x7fffu + ((u >> 16) & 1u);
    return (u16)(u >> 16);
}

__device__ __forceinline__ void gload16(const void* g, void* l) {
    __builtin_amdgcn_global_load_lds(
        (const __attribute__((address_space(1))) void*)g,
        (__attribute__((address_space(3))) void*)l, 16, 0, 0);
}

// ---------------- prep1: gate1 + wconv + row-major patchify (R13-verified) ----------------
__global__ __launch_bounds__(256) void prep1_kernel(
    const float* __restrict__ x,
    const float* __restrict__ g,
    const float* __restrict__ noise,
    const float* __restrict__ w_gate,
    const float* __restrict__ w_noise,
    const float* __restrict__ w_exp,
    float* __restrict__ gCl, float* __restrict__ gSd, float* __restrict__ gNy,
    u16* __restrict__ patches,
    u16* __restrict__ wb)
{
    __shared__ float sW[DIN][NE + 1];
    __shared__ float sWn[DIN][NE + 1];
    const int t = threadIdx.x;
    int bid = blockIdx.x;

    if (bid < GATE_BLOCKS) {
        for (int i = t; i < DIN * NE; i += 256) {
            sW[i >> 3][i & 7]  = w_gate[i];
            sWn[i >> 3][i & 7] = w_noise[i];
        }
        __syncthreads();
        const int pair = t >> 2, q = t & 3;
        const int bl = pair >> 3, e = pair & 7;
        const int b = bid * 8 + bl;
        float cl = 0.f, nz = 0.f;
        const float* gr = g + b * DIN + q * 80;
        #pragma unroll 4
        for (int j = 0; j < 80; ++j) {
            float gv = gr[j];
            cl = fmaf(gv, sW[q * 80 + j][e], cl);
            nz = fmaf(gv, sWn[q * 80 + j][e], nz);
        }
        cl += __shfl_xor(cl, 1); cl += __shfl_xor(cl, 2);
        nz += __shfl_xor(nz, 1); nz += __shfl_xor(nz, 2);
        if (q == 0) {
            int p = b * NE + e;
            // jax.nn.softplus == max(x,0)+log1p(exp(-|x|))
            float sd = fmaxf(nz, 0.f) + log1pf(expf(-fabsf(nz))) + 0.01f;
            gCl[p] = cl; gSd[p] = sd;
            gNy[p] = fmaf(noise[p], sd, cl);
        }
        return;
    }
    bid -= GATE_BLOCKS;

    if (bid < WCONV_BLOCKS) {
        int idx = bid * 256 + t;
        const float* src = w_exp + (size_t)idx * 16;
        u16* dst = wb + (size_t)idx * 16;
        float4 f0 = *reinterpret_cast<const float4*>(src);
        float4 f1 = *reinterpret_cast<const float4*>(src + 4);
        float4 f2 = *reinterpret_cast<const float4*>(src + 8);
        float4 f3 = *reinterpret_cast<const float4*>(src + 12);
        uint4 o0, o1;
        o0.x = (u32)f2bf(f0.x) | ((u32)f2bf(f0.y) << 16);
        o0.y = (u32)f2bf(f0.z) | ((u32)f2bf(f0.w) << 16);
        o0.z = (u32)f2bf(f1.x) | ((u32)f2bf(f1.y) << 16);
        o0.w = (u32)f2bf(f1.z) | ((u32)f2bf(f1.w) << 16);
        o1.x = (u32)f2bf(f2.x) | ((u32)f2bf(f2.y) << 16);
        o1.y = (u32)f2bf(f2.z) | ((u32)f2bf(f2.w) << 16);
        o1.z = (u32)f2bf(f3.x) | ((u32)f2bf(f3.y) << 16);
        o1.w = (u32)f2bf(f3.z) | ((u32)f2bf(f3.w) << 16);
        *reinterpret_cast<uint4*>(dst)     = o0;
        *reinterpret_cast<uint4*>(dst + 8) = o1;
        return;
    }
    bid -= WCONV_BLOCKS;

    // patchify -> bf16 row-major [b][256-stride][768], rows < 196 only
    int idx = bid * 256 + t;
    int ph = idx & 15;
    int c  = (idx >> 4) % 3;
    int p  = (idx / 48) % NP;
    int b  = idx / (48 * NP);
    const float* src = x + (((size_t)(b * 3 + c) * 224 + (p / 14) * 16 + ph) * 224
                            + (p % 14) * 16);
    u16* dst = patches + ((size_t)b * 256 + p) * CK + c * 256 + ph * 16;
    float4 f0 = *reinterpret_cast<const float4*>(src);
    float4 f1 = *reinterpret_cast<const float4*>(src + 4);
    float4 f2 = *reinterpret_cast<const float4*>(src + 8);
    float4 f3 = *reinterpret_cast<const float4*>(src + 12);
    uint4 o0, o1;
    o0.x = (u32)f2bf(f0.x) | ((u32)f2bf(f0.y) << 16);
    o0.y = (u32)f2bf(f0.z) | ((u32)f2bf(f0.w) << 16);
    o0.z = (u32)f2bf(f1.x) | ((u32)f2bf(f1.y) << 16);
    o0.w = (u32)f2bf(f1.z) | ((u32)f2bf(f1.w) << 16);
    o1.x = (u32)f2bf(f2.x) | ((u32)f2bf(f2.y) << 16);
    o1.y = (u32)f2bf(f2.z) | ((u32)f2bf(f2.w) << 16);
    o1.z = (u32)f2bf(f3.x) | ((u32)f2bf(f3.y) << 16);
    o1.w = (u32)f2bf(f3.z) | ((u32)f2bf(f3.w) << 16);
    *reinterpret_cast<uint4*>(dst)     = o0;
    *reinterpret_cast<uint4*>(dst + 8) = o1;
}

// ---------------- gate2: top-2, probs, loss, eid, expert-sorted perm ----------------
__global__ __launch_bounds__(512) void gate2_kernel(
    const float* __restrict__ gCl,
    const float* __restrict__ gSd,
    const float* __restrict__ gNy,
    int* __restrict__ eid,
    int* __restrict__ perm,
    float* __restrict__ loss_out)
{
    __shared__ float sNy[NB][NE];
    __shared__ float sProb[NB][NE];
    __shared__ int   sTop[NB];
    __shared__ float sImp[NE], sLoad[NE];
    const int t = threadIdx.x;
    const int b = t >> 3, e = t & 7;
    float cl = gCl[t], sd = gSd[t], ny = gNy[t];
    sNy[b][e] = ny;
    __syncthreads();
    float v1 = -1e30f, v2 = -1e30f; int i1 = 0;
    #pragma unroll
    for (int k2 = 0; k2 < NE; ++k2) {
        float v = sNy[b][k2];
        if (v > v1) { v2 = v1; v1 = v; i1 = k2; }
        else if (v > v2) { v2 = v; }
    }
    if (e == 0) { sTop[b] = i1; eid[b] = i1; }
    // is_in: noisy > 2nd-largest (thr_in=v2); else threshold = largest (v1)
    float thr = (ny > v2) ? v2 : v1;
    float z = (cl - thr) / sd;
    sProb[b][e] = 0.5f * (1.0f + erff(z * 0.7071067811865476f));
    __syncthreads();
    if (t < NE) {
        float imp = 0.f, ld = 0.f;
        for (int i = 0; i < NB; ++i) {
            imp += (sTop[i] == t) ? 1.0f : 0.0f;
            ld  += sProb[i][t];
        }
        sImp[t] = imp; sLoad[t] = ld;
    }
    __syncthreads();
    if (t == 0) {
        float mi = 0.f, ml = 0.f;
        for (int k2 = 0; k2 < NE; ++k2) { mi += sImp[k2]; ml += sLoad[k2]; }
        mi *= (1.0f / NE); ml *= (1.0f / NE);
        float vi = 0.f, vl = 0.f;
        for (int k2 = 0; k2 < NE; ++k2) {
            float d1 = sImp[k2] - mi;  vi += d1 * d1;
            float d2 = sLoad[k2] - ml; vl += d2 * d2;
        }
        vi *= (1.0f / (NE - 1)); vl *= (1.0f / (NE - 1));  // ddof=1
        loss_out[0] = (vi / (mi * mi + 1e-10f) + vl / (ml * ml + 1e-10f)) * 0.01f;
        // expert-sorted stable permutation (per-XCD B locality)
        int off[NE]; int s = 0;
        #pragma unroll
        for (int k2 = 0; k2 < NE; ++k2) { off[k2] = s; s += (int)sImp[k2]; }
        for (int i = 0; i < NB; ++i) perm[off[sTop[i]]++] = i;
    }
}

// ---------------- expert GEMM: 128x192 tile, BK=64, dbuf, counted vmcnt ----------------
// 512 blocks = (sorted slot -> image, mt 0/1, nt 0..3); 256 thr = 4 waves
// (2M x 2N), wave tile 64x96 = 4x6 frags, BK=64 -> 48 MFMA per phase, 12
// K-iters, 24 barriers/block (vs R5's 48). LDS 80KB dbuf -> exactly 2
// blocks/CU, grid 512 = perfect 2-deep block wave. Row = 128B = 8 chunks;
// bank swizzle chunk' = chunk ^ (row&7) (involution; staging source chunk
// cg = (l&7)^(l>>3), wave-uniform LDS dest + lane*16 preserved).
__global__ void __launch_bounds__(256, 2) gemm_kernel(
    const u16* __restrict__ patches,
    const u16* __restrict__ wbf,
    const float* __restrict__ b_exp,
    const int* __restrict__ eid,
    const int* __restrict__ perm,
    float* __restrict__ out)
{
    extern __shared__ char sm[];   // 2 x 40960 (A 16KB | B 24KB)

    const int id = blockIdx.x;
    const int v  = (id & 7) * 64 + (id >> 3);   // bijective: 512 = 8*64
    const int b  = perm[v >> 3];
    const int rr = v & 7;
    const int m0 = (rr >> 2) * 128;
    const int n0 = (rr & 3) * 192;
    const int e  = eid[b];

    const int t  = threadIdx.x;
    const int l  = t & 63;
    const int w  = t >> 6;
    const int wm = w >> 1;        // 0/1: 64-row half
    const int wn = w & 1;         // 0/1: 96-col half

    // ---- staging addresses ----
    const u32 cg = (u32)((l & 7) ^ (l >> 3));     // pre-swizzled source chunk
    const u16* aS[4];
    const u16* bS[6];
    u32 aD[4], bD[6];
    #pragma unroll
    for (int j = 0; j < 4; ++j) {
        int row = w * 32 + j * 8 + (l >> 3);
        aS[j] = patches + ((size_t)b * 256 + m0 + row) * CK + cg * 8;
        aD[j] = (u32)(w * 4096 + (j * 64 + l) * 16);
    }
    #pragma unroll
    for (int j = 0; j < 6; ++j) {
        int row = w * 48 + j * 8 + (l >> 3);
        bS[j] = wbf + (size_t)e * ESTR + ((size_t)n0 + row) * CK + cg * 8;
        bD[j] = 16384u + (u32)(w * 6144 + (j * 64 + l) * 16);
    }

    // ---- fragment read offsets: chunk' = (ks*4 + (l>>4)) ^ (row&7), row&7 = l&7 ----
    u32 aOff[2][4], bOff[2][6];
    #pragma unroll
    for (int ks = 0; ks < 2; ++ks) {
        #pragma unroll
        for (int fm = 0; fm < 4; ++fm) {
            int row = wm * 64 + fm * 16 + (l & 15);
            aOff[ks][fm] = (u32)(row * 128) + (((u32)(ks * 4 + (l >> 4)) ^ (u32)(l & 7)) << 4);
        }
        #pragma unroll
        for (int fn = 0; fn < 6; ++fn) {
            int row = wn * 96 + fn * 16 + (l & 15);
            bOff[ks][fn] = 16384u + (u32)(row * 128)
                         + (((u32)(ks * 4 + (l >> 4)) ^ (u32)(l & 7)) << 4);
        }
    }

    f32x4 acc[4][6];
    #pragma unroll
    for (int fm = 0; fm < 4; ++fm)
        #pragma unroll
        for (int fn = 0; fn < 6; ++fn)
            acc[fm][fn] = (f32x4){0.f, 0.f, 0.f, 0.f};

    auto STAGE = [&](u32 bo, int kt) {
        #pragma unroll
        for (int j = 0; j < 4; ++j) gload16(aS[j] + kt * 64, sm + bo + aD[j]);
        #pragma unroll
        for (int j = 0; j < 6; ++j) gload16(bS[j] + kt * 64, sm + bo + bD[j]);
    };
    auto COMP = [&](u32 bo) {
        #pragma unroll
        for (int ks = 0; ks < 2; ++ks) {
            bf16x8 af[4], bfr[6];
            #pragma unroll
            for (int fm = 0; fm < 4; ++fm)
                af[fm] = *reinterpret_cast<const bf16x8*>(sm + bo + aOff[ks][fm]);
            #pragma unroll
            for (int fn = 0; fn < 6; ++fn)
                bfr[fn] = *reinterpret_cast<const bf16x8*>(sm + bo + bOff[ks][fn]);
            __builtin_amdgcn_s_setprio(1);
            #pragma unroll
            for (int fm = 0; fm < 4; ++fm)
                #pragma unroll
                for (int fn = 0; fn < 6; ++fn)
                    acc[fm][fn] = __builtin_amdgcn_mfma_f32_16x16x32_bf16(
                        af[fm], bfr[fn], acc[fm][fn], 0, 0, 0);
            __builtin_amdgcn_s_setprio(0);
        }
    };

    // ---- prologue: tile 0 -> buf 0 ----
    STAGE(0, 0);

    // ---- main loop: 11 iters, compute kt / prefetch kt+1, ONE vmcnt wait ----
    for (int kt = 0; kt < NKT2 - 1; ++kt) {
        STAGE((u32)(((kt + 1) & 1) * 40960), kt + 1);
        asm volatile("s_waitcnt vmcnt(10)" ::: "memory");   // drain tile kt only
        __builtin_amdgcn_s_barrier();
        COMP((u32)((kt & 1) * 40960));
        __builtin_amdgcn_s_barrier();
    }
    // ---- epilogue tile 11 ----
    asm volatile("s_waitcnt vmcnt(0)" ::: "memory");
    __builtin_amdgcn_s_barrier();
    COMP((u32)(((NKT2 - 1) & 1) * 40960));

    // ---- store: bias + eps-replace, rows < 196 only ----
    const int r4 = (l >> 4) * 4;
    #pragma unroll
    for (int fm = 0; fm < 4; ++fm) {
        int mb = m0 + wm * 64 + fm * 16 + r4;
        #pragma unroll
        for (int fn = 0; fn < 6; ++fn) {
            int col = n0 + wn * 96 + fn * 16 + (l & 15);
            float bias = b_exp[e * CN + col];
            #pragma unroll
            for (int q = 0; q < 4; ++q) {
                int mrow = mb + q;
                if (mrow < NP) {
                    float vv = acc[fm][fn][q] + bias;
                    if (vv == 0.0f) vv = 2.220446049250313e-16f;
                    out[((size_t)b * NP + mrow) * CN + col] = vv;
                }
            }
        }
    }
}

extern "C" void kernel_launch(void* const* d_in, const int* in_sizes, int n_in,
                              void* d_out, int out_size, void* d_ws, size_t ws_size,
                              hipStream_t stream) {
    const float* x       = (const float*)d_in[0];
    const float* g       = (const float*)d_in[1];
    const float* noise   = (const float*)d_in[2];
    const float* w_gate  = (const float*)d_in[3];
    const float* w_noise = (const float*)d_in[4];
    const float* w_exp   = (const float*)d_in[5];
    const float* b_exp   = (const float*)d_in[6];
    float* out = (float*)d_out;

    char* ws = (char*)d_ws;
    int*   eid     = (int*)ws;                    // 256 B
    int*   perm    = (int*)(ws + 256);            // 256 B
    float* gCl     = (float*)(ws + 512);
    float* gSd     = (float*)(ws + 2560);
    float* gNy     = (float*)(ws + 4608);
    u16*   patches = (u16*)(ws + 8192);                             // 64*256*768*2
    u16*   wbf     = (u16*)(ws + 8192 + (size_t)NB * 256 * CK * 2); // 8*768*768*2

    hipFuncSetAttribute((const void*)gemm_kernel,
                        hipFuncAttributeMaxDynamicSharedMemorySize, 81920);

    hipLaunchKernelGGL(prep1_kernel,
                       dim3(GATE_BLOCKS + WCONV_BLOCKS + PATCH_BLOCKS), dim3(256), 0, stream,
                       x, g, noise, w_gate, w_noise, w_exp, gCl, gSd, gNy, patches, wbf);
    hipLaunchKernelGGL(gate2_kernel, dim3(1), dim3(512), 0, stream,
                       gCl, gSd, gNy, eid, perm, out + (size_t)NB * NP * CN);
    hipLaunchKernelGGL(gemm_kernel, dim3(512), dim3(256), 81920, stream,
                       patches, wbf, b_exp, eid, perm, out);
}